// Round 4
// baseline (1919.497 us; speedup 1.0000x reference)
//
#include <hip/hip_runtime.h>
#include <stdint.h>

#define NPTS (1u << 21)   // 4*512*1024
#define KC 256
#define KM_ITERS 10
#define CHUNK 4096
#define NCHUNK (NPTS / CHUNK)   // 512

// -------- threefry2x32 (JAX PRNG) with explicit key, both output words ------
__device__ __forceinline__ uint32_t rotl32(uint32_t v, uint32_t s) {
  return (v << s) | (v >> (32u - s));
}

__device__ void threefry2x32_key(uint32_t k0, uint32_t k1,
                                 uint32_t c0, uint32_t c1,
                                 uint32_t* o0, uint32_t* o1) {
  uint32_t ks[3] = {k0, k1, k0 ^ k1 ^ 0x1BD11BDAu};
  uint32_t x0 = c0 + ks[0];
  uint32_t x1 = c1 + ks[1];
  const uint32_t rotA[4] = {13u, 15u, 26u, 6u};
  const uint32_t rotB[4] = {17u, 29u, 16u, 24u};
  #pragma unroll
  for (int i = 0; i < 5; ++i) {
    const uint32_t* rot = ((i & 1) == 0) ? rotA : rotB;
    #pragma unroll
    for (int r = 0; r < 4; ++r) {
      x0 += x1;
      x1 = rotl32(x1, rot[r]);
      x1 ^= x0;
    }
    x0 += ks[(i + 1) % 3];
    x1 += ks[(i + 2) % 3] + (uint32_t)(i + 1);
  }
  *o0 = x0;
  *o1 = x1;
}

// sort centers ascending (bitonic, value+orig index); rep[j] = min orig index
// among slots with equal value (exact-duplicate tie groups). Shared body so
// the init-fused variant reuses it.
__device__ __forceinline__ void sort_body(int t, float cval,
                                          float* __restrict__ sortedC,
                                          uint32_t* __restrict__ rep) {
  __shared__ float v[KC];
  __shared__ int sidx[KC];
  __shared__ uint32_t r[KC];
  v[t] = cval;
  sidx[t] = t;
  __syncthreads();
  for (int size = 2; size <= KC; size <<= 1) {
    for (int stride = size >> 1; stride > 0; stride >>= 1) {
      int partner = t ^ stride;
      if (partner > t) {
        bool ascending = ((t & size) == 0);
        float va = v[t], vb = v[partner];
        int ia = sidx[t], ib = sidx[partner];
        bool doswap = ascending ? (va > vb) : (va < vb);
        if (doswap) { v[t] = vb; v[partner] = va; sidx[t] = ib; sidx[partner] = ia; }
      }
      __syncthreads();
    }
  }
  if (t == 0) {   // run-min of orig indices over equal-value groups (2 passes)
    float cv = v[0];
    uint32_t cur = (uint32_t)sidx[0];
    r[0] = cur;
    for (int j = 1; j < KC; ++j) {
      if (v[j] == cv) { uint32_t ij = (uint32_t)sidx[j]; cur = (ij < cur) ? ij : cur; }
      else { cv = v[j]; cur = (uint32_t)sidx[j]; }
      r[j] = cur;
    }
    float nv = v[KC - 1];
    uint32_t nc = r[KC - 1];
    for (int j = KC - 2; j >= 0; --j) {
      if (v[j] == nv) { nc = (r[j] < nc) ? r[j] : nc; r[j] = nc; }
      else { nv = v[j]; nc = r[j]; }
    }
  }
  __syncthreads();
  sortedC[t] = v[t];
  rep[t] = r[t];
}

__global__ __launch_bounds__(256) void km_sort_centers(
    const float* __restrict__ centers, float* __restrict__ sortedC,
    uint32_t* __restrict__ rep) {
  const int t = threadIdx.x;
  sort_body(t, centers[t], sortedC, rep);
}

// fused: centers0 = x[randint(key(42),(256,),0,N)] [R14/R16-validated] + sort.
// Still writes centers[] (empty-cluster keep-old semantics needs it).
__global__ __launch_bounds__(256) void km_init_sort(
    const float* __restrict__ x, float* __restrict__ centers,
    float* __restrict__ sortedC, uint32_t* __restrict__ rep) {
  const int t = threadIdx.x;
  uint32_t s0, s1;
  threefry2x32_key(0u, 42u, 0u, 1u, &s0, &s1);      // k2 = split(key(42))[1]
  uint32_t b0, b1;
  threefry2x32_key(s0, s1, 0u, (uint32_t)t, &b0, &b1);
  uint32_t gi = (b0 ^ b1) & (NPTS - 1u);
  float c = x[gi];
  centers[t] = c;
  sort_body(t, c, sortedC, rep);
}

// exact-argmin via sorted binary search: upper-bound (count of <= x, capped
// 255), then 2-candidate f32 compare (same |x-c| ops as reference), ties ->
// min rep (first-original-index semantics). Exact dups handled by rep[].
__device__ __forceinline__ uint32_t bs_label(float x, const float* sC,
                                             const uint32_t* rp) {
  int pos = 0;
  #pragma unroll
  for (int d = 128; d >= 1; d >>= 1)
    if (sC[pos + d - 1] <= x) pos += d;
  if (pos == 0) return rp[0];
  float cl = sC[pos - 1], cr = sC[pos & 255];   // pos<=255 always; &255 for safety
  float dl = fabsf(x - cl), dr = fabsf(x - cr);
  if (dl < dr) return rp[pos - 1];
  if (dr < dl) return rp[pos];
  uint32_t a = rp[pos - 1], b = rp[pos];
  return a < b ? a : b;
}

// assign + per-chunk histogram via binary search (R23: replaces 256-sweep).
__global__ __launch_bounds__(256) void km_assign_hist(
    const float* __restrict__ x, const float* __restrict__ sortedC,
    const uint32_t* __restrict__ rep, uint32_t* __restrict__ hist) {
  __shared__ float sC[KC];
  __shared__ uint32_t rp[KC];
  __shared__ uint32_t sH[KC];
  const int t = threadIdx.x, b = blockIdx.x;
  sC[t] = sortedC[t];
  rp[t] = rep[t];
  sH[t] = 0u;
  __syncthreads();

  #pragma unroll
  for (int q = 0; q < 4; ++q) {
    const int i4 = b * (CHUNK / 4) + q * 256 + t;  // float4 index
    float4 xv = reinterpret_cast<const float4*>(x)[i4];
    uint32_t l0 = bs_label(xv.x, sC, rp);
    uint32_t l1 = bs_label(xv.y, sC, rp);
    uint32_t l2 = bs_label(xv.z, sC, rp);
    uint32_t l3 = bs_label(xv.w, sC, rp);
    atomicAdd(&sH[l0], 1u);
    atomicAdd(&sH[l1], 1u);
    atomicAdd(&sH[l2], 1u);
    atomicAdd(&sH[l3], 1u);
  }
  __syncthreads();
  hist[b * KC + t] = sH[t];
}

// parallel per-cluster exclusive scan over chunks (Hillis-Steele, exact ints).
// Totals land in clusterTot[k]; the cluster-level scan moved into km_scatter.
__global__ __launch_bounds__(512) void km_scan_chunks(
    uint32_t* __restrict__ hist, uint32_t* __restrict__ clusterTot) {
  __shared__ uint32_t s[NCHUNK];
  const int k = blockIdx.x, t = threadIdx.x;
  uint32_t v = hist[t * KC + k];
  s[t] = v;
  __syncthreads();
  #pragma unroll
  for (int d = 1; d < NCHUNK; d <<= 1) {
    uint32_t u = (t >= d) ? s[t - d] : 0u;
    __syncthreads();
    s[t] += u;
    __syncthreads();
  }
  hist[t * KC + k] = s[t] - v;            // exclusive within cluster
  if (t == NCHUNK - 1) clusterTot[k] = s[t];  // cluster total
}

// stable scatter into sorted_x (= d_out used as scratch); labels via bs.
// R4: each block LDS-scans the 256 cluster totals itself (replaces the
// km_scan_clusters launch); block 0 publishes the scanned clusterStart2[257]
// for km_fold_update (separate buffer -> no same-dispatch read/write race).
__global__ __launch_bounds__(256) void km_scatter(
    const float* __restrict__ x, const float* __restrict__ sortedC,
    const uint32_t* __restrict__ rep,
    const uint32_t* __restrict__ hist, const uint32_t* __restrict__ clusterTot,
    uint32_t* __restrict__ clusterStart2, float* __restrict__ sorted_x) {
  __shared__ float sC[KC];
  __shared__ uint32_t rp[KC];
  __shared__ uint32_t run[KC];
  __shared__ uint32_t scn[KC];
  __shared__ uint32_t cntw[4][KC];
  __shared__ uint32_t basew[4][KC];
  const int t = threadIdx.x, b = blockIdx.x;
  const int w = t >> 6, lane = t & 63;
  sC[t] = sortedC[t];
  rp[t] = rep[t];
  const uint32_t tot = clusterTot[t];
  scn[t] = tot;
  __syncthreads();
  #pragma unroll
  for (int d = 1; d < KC; d <<= 1) {
    uint32_t u = (t >= d) ? scn[t - d] : 0u;
    __syncthreads();
    scn[t] += u;
    __syncthreads();
  }
  const uint32_t cs = scn[t] - tot;       // exclusive cluster start
  run[t] = hist[b * KC + t] + cs;
  if (b == 0) {
    clusterStart2[t] = cs;
    if (t == KC - 1) clusterStart2[KC] = cs + tot;   // == NPTS
  }
  __syncthreads();

  for (int r = 0; r < CHUNK / 256; ++r) {      // 16 rounds of 256 elements
    const int i = b * CHUNK + r * 256 + t;
    const float xv = x[i];
    uint32_t lab = bs_label(xv, sC, rp);
    unsigned long long m = ~0ULL;
    #pragma unroll
    for (int bit = 0; bit < 8; ++bit) {
      unsigned long long vote = __ballot((lab >> bit) & 1u);
      m &= ((lab >> bit) & 1u) ? vote : ~vote;
    }
    uint32_t rank = (uint32_t)__popcll(m & ((1ULL << lane) - 1ULL));
    uint32_t wcnt = (uint32_t)__popcll(m);
    cntw[0][t] = 0u; cntw[1][t] = 0u; cntw[2][t] = 0u; cntw[3][t] = 0u;
    __syncthreads();
    if (rank == 0) cntw[w][lab] = wcnt;
    __syncthreads();
    {
      uint32_t c0 = cntw[0][t], c1 = cntw[1][t], c2 = cntw[2][t], c3 = cntw[3][t];
      uint32_t base = run[t];
      basew[0][t] = base;
      basew[1][t] = base + c0;
      basew[2][t] = base + c0 + c1;
      basew[3][t] = base + c0 + c1 + c2;
      run[t] = base + c0 + c1 + c2 + c3;
    }
    __syncthreads();
    sorted_x[basew[w][lab] + rank] = xv;
  }
}

// ---- fold helpers: explicit register names, no token pasting ---------------
#define LOADG(p0, p1, p2, p3, p4, p5, p6, p7, base) \
  p0 = b4[(base) + 0]; p1 = b4[(base) + 1];         \
  p2 = b4[(base) + 2]; p3 = b4[(base) + 3];         \
  p4 = b4[(base) + 4]; p5 = b4[(base) + 5];         \
  p6 = b4[(base) + 6]; p7 = b4[(base) + 7];

#define FOLD4(q) s += (q).x; s += (q).y; s += (q).z; s += (q).w;

#define FOLDG(p0, p1, p2, p3, p4, p5, p6, p7) \
  FOLD4(p0) FOLD4(p1) FOLD4(p2) FOLD4(p3)     \
  FOLD4(p4) FOLD4(p5) FOLD4(p6) FOLD4(p7)

// per-cluster sequential f32 left-fold in index order (bitwise == CPU
// scatter-add). R0-validated 256-tile LDS double-buffer + pipelined b128
// reads (161 us). R1-R3 post-mortem: this IS the serial-chain floor
// (~92k-elem max cluster x ~4.2 cyc dependent v_add_f32); global-direct and
// readlane feeds regressed (scalarization / SGPR hazard), deep pipelining
// was neutral. Do not restructure.
__global__ __launch_bounds__(64) void km_fold_update(
    const float* __restrict__ sorted_x, const uint32_t* __restrict__ clusterStart,
    float* __restrict__ centers) {
  __shared__ __align__(16) float buf[2][256];
  const int k = blockIdx.x;
  const uint32_t lane = threadIdx.x;
  const uint32_t s0 = clusterStart[k], s1 = clusterStart[k + 1];
  const uint32_t cnt = s1 - s0;
  const float* p = sorted_x + s0;
  const uint32_t ntiles = (cnt + 255u) >> 8;

  if (ntiles > 0) {
    uint32_t i0 = lane * 4u;
    float4 v = make_float4(0.f, 0.f, 0.f, 0.f);
    if (i0 + 3u < cnt) {
      v = *reinterpret_cast<const float4*>(p + i0);
    } else {
      if (i0 + 0u < cnt) v.x = p[i0 + 0u];
      if (i0 + 1u < cnt) v.y = p[i0 + 1u];
      if (i0 + 2u < cnt) v.z = p[i0 + 2u];
    }
    *reinterpret_cast<float4*>(&buf[0][lane * 4u]) = v;
  }
  __syncthreads();

  float s = 0.0f;
  for (uint32_t t = 0; t < ntiles; ++t) {
    const bool have_next = (t + 1u < ntiles);
    float4 vn = make_float4(0.f, 0.f, 0.f, 0.f);
    if (have_next) {
      uint32_t i0 = (t + 1u) * 256u + lane * 4u;
      if (i0 + 3u < cnt) {
        vn = *reinterpret_cast<const float4*>(p + i0);
      } else {
        if (i0 + 0u < cnt) vn.x = p[i0 + 0u];
        if (i0 + 1u < cnt) vn.y = p[i0 + 1u];
        if (i0 + 2u < cnt) vn.z = p[i0 + 2u];
      }
    }
    if (lane == 0) {
      const float* bb = buf[t & 1u];
      uint32_t m = cnt - t * 256u;
      if (m > 256u) m = 256u;
      if (m == 256u) {
        const float4* b4 = reinterpret_cast<const float4*>(bb);
        float4 a0, a1, a2, a3, a4, a5, a6, a7;
        float4 c0, c1, c2, c3, c4, c5, c6, c7;
        LOADG(a0, a1, a2, a3, a4, a5, a6, a7, 0)
        LOADG(c0, c1, c2, c3, c4, c5, c6, c7, 8)
        FOLDG(a0, a1, a2, a3, a4, a5, a6, a7)
        LOADG(a0, a1, a2, a3, a4, a5, a6, a7, 16)
        FOLDG(c0, c1, c2, c3, c4, c5, c6, c7)
        LOADG(c0, c1, c2, c3, c4, c5, c6, c7, 24)
        FOLDG(a0, a1, a2, a3, a4, a5, a6, a7)
        LOADG(a0, a1, a2, a3, a4, a5, a6, a7, 32)
        FOLDG(c0, c1, c2, c3, c4, c5, c6, c7)
        LOADG(c0, c1, c2, c3, c4, c5, c6, c7, 40)
        FOLDG(a0, a1, a2, a3, a4, a5, a6, a7)
        LOADG(a0, a1, a2, a3, a4, a5, a6, a7, 48)
        FOLDG(c0, c1, c2, c3, c4, c5, c6, c7)
        LOADG(c0, c1, c2, c3, c4, c5, c6, c7, 56)
        FOLDG(a0, a1, a2, a3, a4, a5, a6, a7)
        FOLDG(c0, c1, c2, c3, c4, c5, c6, c7)
      } else {
        uint32_t j = 0;
        for (; j + 16u <= m; j += 16u) {
          float v0 = bb[j + 0], v1 = bb[j + 1], v2 = bb[j + 2], v3 = bb[j + 3];
          float v4 = bb[j + 4], v5 = bb[j + 5], v6 = bb[j + 6], v7 = bb[j + 7];
          float v8 = bb[j + 8], v9 = bb[j + 9], va = bb[j + 10], vb = bb[j + 11];
          float vc = bb[j + 12], vd = bb[j + 13], ve = bb[j + 14], vf = bb[j + 15];
          s += v0; s += v1; s += v2; s += v3;
          s += v4; s += v5; s += v6; s += v7;
          s += v8; s += v9; s += va; s += vb;
          s += vc; s += vd; s += ve; s += vf;
        }
        for (; j < m; ++j) s += bb[j];
      }
    }
    if (have_next) {
      *reinterpret_cast<float4*>(&buf[(t + 1u) & 1u][lane * 4u]) = vn;
    }
    __syncthreads();
  }
  if (lane == 0 && cnt > 0) centers[k] = s / (float)cnt;  // else keep old
}

// final assign + gather via binary search: out = centers[labels]
__global__ __launch_bounds__(256) void km_final(
    const float* __restrict__ x, const float* __restrict__ centers,
    const float* __restrict__ sortedC, const uint32_t* __restrict__ rep,
    float* __restrict__ out) {
  __shared__ float sC[KC];
  __shared__ uint32_t rp[KC];
  __shared__ float sCtr[KC];
  const int t = threadIdx.x;
  sC[t] = sortedC[t];
  rp[t] = rep[t];
  sCtr[t] = centers[t];
  __syncthreads();

  const int nv = (int)(NPTS / 4u);
  for (int i = blockIdx.x * blockDim.x + t; i < nv; i += gridDim.x * blockDim.x) {
    float4 xv = reinterpret_cast<const float4*>(x)[i];
    float4 o;
    o.x = sCtr[bs_label(xv.x, sC, rp)];
    o.y = sCtr[bs_label(xv.y, sC, rp)];
    o.z = sCtr[bs_label(xv.z, sC, rp)];
    o.w = sCtr[bs_label(xv.w, sC, rp)];
    reinterpret_cast<float4*>(out)[i] = o;
  }
}

extern "C" void kernel_launch(void* const* d_in, const int* in_sizes, int n_in,
                              void* d_out, int out_size, void* d_ws, size_t ws_size,
                              hipStream_t stream) {
  const float* x = (const float*)d_in[0];
  float* out = (float*)d_out;

  // ws layout (~520 KB):
  //   [0,1K)       centers f32[256]
  //   [1K,2.1K)    clusterTot u32[256]   (totals from scan_chunks)
  //   [2.5K,3.5K)  sortedC f32[256]
  //   [3.5K,4.5K)  rep u32[256]
  //   [4.5K,5.6K)  clusterStart2 u32[257] (scanned, written by scatter b0)
  //   [8K,520K)    hist u32[512][256]
  // sorted_x (8 MB) lives in d_out — dead after fold, overwritten by km_final.
  uint8_t* ws = (uint8_t*)d_ws;
  float* centers = (float*)(ws + 0);
  uint32_t* clusterTot = (uint32_t*)(ws + 1024);
  float* sortedC = (float*)(ws + 2560);
  uint32_t* rep = (uint32_t*)(ws + 3584);
  uint32_t* clusterStart2 = (uint32_t*)(ws + 4608);
  uint32_t* hist = (uint32_t*)(ws + 8192);
  float* sorted_x = (float*)d_out;

  km_init_sort<<<1, KC, 0, stream>>>(x, centers, sortedC, rep);
  for (int it = 0; it < KM_ITERS; ++it) {
    if (it > 0) km_sort_centers<<<1, KC, 0, stream>>>(centers, sortedC, rep);
    km_assign_hist<<<NCHUNK, 256, 0, stream>>>(x, sortedC, rep, hist);
    km_scan_chunks<<<KC, NCHUNK, 0, stream>>>(hist, clusterTot);
    km_scatter<<<NCHUNK, 256, 0, stream>>>(x, sortedC, rep, hist, clusterTot,
                                           clusterStart2, sorted_x);
    km_fold_update<<<KC, 64, 0, stream>>>(sorted_x, clusterStart2, centers);
  }
  km_sort_centers<<<1, KC, 0, stream>>>(centers, sortedC, rep);
  km_final<<<1024, 256, 0, stream>>>(x, centers, sortedC, rep, out);
}